// Round 3
// baseline (175.713 us; speedup 1.0000x reference)
//
#include <hip/hip_runtime.h>
#include <hip/hip_bf16.h>

// FlowNetC correlation: B=4, C=256, H=W=96, PAD=MAX_DISP=20, STRIDE2=2, D=21.
// out[b, oy*21+ox, h, w] = (1/C) * sum_c x1[b,c,h,w] * x2[b,c,h+2oy-20,w+2ox-20]
//
// dx even -> split w by parity. Per (b,h,oy,par): out[i,e] = sum_c A[c,i]*B[c,i+e-10]
// (i=w>>1 in [0,48), e=ox). Band GEMM, MFMA 16x16x32 bf16.
//
// h-QUAD pairing: planes (hA+2j, oy=t-j), j=0..3, all share image x2[b, hA+2t-20]
// -> 4 MFMAs per B-fragment ds_read. PARITY split: B rows [par*48, par*48+48)
// are only read by parity-par waves, so a block is 3 waves (mt=0,1,2) of ONE
// parity staging a 24KB half-image. LDS = 2-slot ring (48KB) + quad slab
// (16.1KB) = 65.6KB -> 2 blocks/CU co-resident: one block's MFMA phase hides
// the other's DMA/scatter/barrier phases (round-2 analysis: single-block
// serialization of the LDS pipe was the bottleneck).
//
// Ring discipline (2 slots): image k in slot k%2. Prefetch P(k+2)->slot k%2
// happens AFTER the (e) barrier of iter k (all waves done reading slot k%2).
// vmcnt ledger (per wave, in-order retirement): P=8 gl2lds per image,
// S>=5 stores per iter (>=1 valid plane x >=5). At (b) of iter k need P(k)
// retired; ops issued after it: k==0 -> P(1)=8 (or 0 if nv==1); k==1 ->
// P(2)+S(0)=13 (or S(0)=5 if nv==2); steady -> S(k-2)+P(k+1)+S(k-1)=18;
// last -> S(k-2)+S(k-1)=10. Pin fences (asm "" memory) keep stores after
// prefetches inside each window. A-fragment loads are drained with a
// compiler-visible s_waitcnt(0) BEFORE the prologue prefetches so the
// compiler never inserts a vmcnt wait inside the loop.
//
// Global layout XOR-swizzle per row (chunk' = chunk ^ (row&31)) keeps
// ds_read_b128 at 512B row stride bank-conflict-reduced; keys use the GLOBAL
// row index (par*48 + local) while LDS offsets use the local row.

typedef __bf16 bf16x8 __attribute__((ext_vector_type(8)));
typedef float f32x4 __attribute__((ext_vector_type(4)));

#define B_ 4
#define C_ 256
#define H_ 96
#define W_ 96
#define NOFF 21
#define ROWS 96                         // rows per (b,h) image = 2 par * 48
#define IMG_ELEMS (ROWS * C_)           // 24576 ushorts = 48KB
#define HALF_ELEMS (48 * C_)            // 12288 ushorts = 24KB per parity
#define X1T_ELEMS (B_ * H_ * IMG_ELEMS) // 9,437,184 ushorts

__device__ __forceinline__ unsigned short f32_to_bf16_rne(float f) {
    union { float f; unsigned u; } v; v.f = f;
    unsigned u = v.u;
    return (unsigned short)((u + 0x7fffu + ((u >> 16) & 1u)) >> 16);
}

__device__ __forceinline__ void gl2lds16(const void* g, void* l) {
    __builtin_amdgcn_global_load_lds(
        (const __attribute__((address_space(1))) void*)g,
        (__attribute__((address_space(3))) void*)l, 16, 0, 0);
}

// ---------------------------------------------------------------------------
// Prep: fp32 NCHW -> bf16 swizzled-transposed [b][h][row][chunk^(row&31)]
// row = par*48 + (w>>1), par = w&1. One block per (b,h,src,c-block-of-64).
// ---------------------------------------------------------------------------
__global__ __launch_bounds__(256) void prep_kernel(const float* __restrict__ x1,
                                                   const float* __restrict__ x2,
                                                   unsigned short* __restrict__ ws) {
    __shared__ float tile[96 * 65];   // [w][c_local], pitch 65: conflict-free
    int bid = blockIdx.x;
    int cblk  = bid & 3;
    int which = (bid >> 2) & 1;
    int bh    = bid >> 3;             // 0..383
    int h = bh % H_;
    int b = bh / H_;
    int c0 = cblk << 6;

    const float* src = (which ? x2 : x1) + ((size_t)(b * C_ + c0) * H_ + h) * W_;
    unsigned short* dst = ws + (size_t)which * X1T_ELEMS + (size_t)(b * H_ + h) * IMG_ELEMS;

    // Phase A: coalesced global reads -> LDS [w][c]
    for (int idx = threadIdx.x; idx < 64 * 96; idx += 256) {
        int c = idx / 96, w = idx - c * 96;
        tile[w * 65 + c] = src[c * (H_ * W_) + w];
    }
    __syncthreads();

    // Phase B: pack 8 c -> 16B store. Per row this c-block lands in one
    // contiguous 128B run (aligned 8-chunk group XOR'd by row bits). Dest-driven.
    for (int idx = threadIdx.x; idx < 96 * 8; idx += 256) {
        int row = idx >> 3, tp = idx & 7;
        int par = row / 48, i = row - par * 48;
        int w = 2 * i + par;
        int s = tp ^ (row & 7);                 // source chunk within c-block
        const float* fsrc = &tile[w * 65 + (s << 3)];
        unsigned pk[4];
#pragma unroll
        for (int e = 0; e < 4; ++e) {
            unsigned lo = f32_to_bf16_rne(fsrc[2 * e]);
            unsigned hi = f32_to_bf16_rne(fsrc[2 * e + 1]);
            pk[e] = lo | (hi << 16);
        }
        int ccp = (((c0 >> 3) ^ (row & 24)) + tp);   // swizzled chunk position
        *(uint4*)((char*)(dst + (size_t)row * C_) + (ccp << 4)) =
            make_uint4(pk[0], pk[1], pk[2], pk[3]);
    }
}

// ---------------------------------------------------------------------------
// Main: block = (b, h-quad, oy-quarter, parity). 3 waves = mt.
// ---------------------------------------------------------------------------
__global__ __launch_bounds__(192, 2) void corr_kernel(const unsigned short* __restrict__ ws,
                                                      float* __restrict__ out) {
    __shared__ unsigned short Bs[2][HALF_ELEMS];  // 2 x 24KB ring
    __shared__ float sl[4][NOFF][49];             // quad transpose slab (by i=w>>1)
    static_assert(sizeof(Bs) + sizeof(sl) <= 81920, "need 2 blocks/CU");

    int bid = blockIdx.x;
    int xcd = bid & 7, sidx = bid >> 3;    // XCD-aware: each XCD owns (b, h-half)
    int b  = xcd >> 1;
    int hh = xcd & 1;
    int par = sidx & 1;
    int t2  = sidx >> 1;
    int og  = t2 & 3;                      // oy quarter
    int qq  = t2 >> 2;                     // quad within half [0,12)
    int gq = qq >> 1, ph = qq & 1;
    int hA = 48 * hh + 8 * gq + ph;        // planes at hA, hA+2, hA+4, hA+6
    int olo = (og * NOFF) >> 2;            // 0,5,10,15
    int ohi = ((og + 1) * NOFF) >> 2;      // 5,10,15,21

    int tid = threadIdx.x;
    int wv = tid >> 6, lane = tid & 63;
    int mt = wv;
    int i0 = mt << 4;
    int n = lane & 15, quad = lane >> 4;

    // Valid oy bands per plane j (h_j = hA+2j): 0 <= h_j + 2oy - 20 < 96,
    // clipped to this block's quarter. Non-empty set contiguous in j; the
    // t-union (t = oy + j) is contiguous.
    int Loj[4], Hij[4];
    int tlo = 1 << 30, thi = -(1 << 30);
#pragma unroll
    for (int j = 0; j < 4; ++j) {
        int hj = hA + 2 * j;
        int lo = (hj >= 21) ? 0 : ((21 - hj) >> 1);
        int hi = ((115 - hj) >> 1) + 1;
        if (lo < olo) lo = olo;
        if (hi > ohi) hi = ohi;
        Loj[j] = lo; Hij[j] = hi;
        if (lo < hi) {
            int a = lo + j, c = hi + j;
            if (a < tlo) tlo = a;
            if (c > thi) thi = c;
        }
    }
    int nv = thi - tlo; if (nv < 0) nv = 0;

    // A fragments for all 4 planes: loaded once from global, reused for all t.
    int rowA = par * 48 + i0 + n;
    int keyA = rowA & 31;
    bf16x8 af[4][8];
#pragma unroll
    for (int pl = 0; pl < 4; ++pl) {
        const unsigned short* Ag =
            ws + (size_t)(b * H_ + hA + 2 * pl) * IMG_ELEMS + (size_t)rowA * C_;
#pragma unroll
        for (int ks = 0; ks < 8; ++ks)
            af[pl][ks] = *(const bf16x8*)(Ag + ((((ks << 2) | quad) ^ keyA) << 3));
    }
    // Pin the loads, then drain them with a COMPILER-VISIBLE wait before any
    // prefetch is issued -> no compiler vmcnt waits inside the pipelined loop.
    asm volatile("" ::: "memory");
    __builtin_amdgcn_s_waitcnt(0);

    const unsigned short* Bimg = ws + (size_t)X1T_ELEMS + (size_t)(b * H_) * IMG_ELEMS;

    int wvoff  = wv * 8192;            // wave-uniform LDS base offset (3 waves x 8KB)
    int gmaoff = wvoff + lane * 16;    // per-lane global offset

#define STAGE(slot, tt) do {                                                          \
    const char* Bg_ = (const char*)(Bimg + (size_t)(hA + 2 * (tt) - 20) * IMG_ELEMS   \
                                    + par * HALF_ELEMS);                              \
    _Pragma("unroll")                                                                 \
    for (int c = 0; c < 8; ++c)                                                       \
        gl2lds16(Bg_ + gmaoff + c * 1024, (char*)Bs[slot] + wvoff + c * 1024);        \
} while (0)

    // Prologue prefetch: images t = tlo, tlo+1 into slots 0,1.
    if (nv > 0) STAGE(0, tlo);
    if (nv > 1) STAGE(1, tlo + 1);
    asm volatile("" ::: "memory");   // pin: zero-fill stores stay after prefetches

    // Zero-fill out-of-band planes (overlaps prologue DMA in flight).
#pragma unroll
    for (int pl = 0; pl < 4; ++pl) {
        int hp = hA + 2 * pl;
        for (int oy = olo; oy < ohi; ++oy) {
            if (oy >= Loj[pl] && oy < Hij[pl]) continue;
            int outb = ((b * 441 + oy * NOFF) * H_ + hp) * W_;
#pragma unroll
            for (int jj = 0; jj < 6; ++jj) {
                int idx = tid + jj * 192;
                if (idx < NOFF * 48) {
                    int ox = idx / 48, i = idx - ox * 48;
                    out[outb + ox * (H_ * W_) + 2 * i + par] = 0.0f;
                }
            }
        }
    }

    int locB[3] = { n, n + 16, n + 32 };                 // local rows in half-image
    int keyB[3] = { (n + 16 * par) & 31,                 // global row & 31
                    (n + 16 + 16 * par) & 31,
                    (n + 32 + 16 * par) & 31 };
    bool useu[3] = { mt != 2, true, mt != 0 };

    for (int k = 0; k < nv; ++k) {
        int t = tlo + k;
        int cur = k & 1;

        // (b) counted wait for P(k) retirement + barrier (all waves' DMA landed).
        if (k == 0) {
            if (nv > 1) asm volatile("s_waitcnt vmcnt(8)\ns_barrier" ::: "memory");
            else        asm volatile("s_waitcnt vmcnt(0)\ns_barrier" ::: "memory");
        } else if (k == 1) {
            if (nv > 2) asm volatile("s_waitcnt vmcnt(13)\ns_barrier" ::: "memory");
            else        asm volatile("s_waitcnt vmcnt(5)\ns_barrier" ::: "memory");
        } else if (k + 1 == nv) {
            asm volatile("s_waitcnt vmcnt(10)\ns_barrier" ::: "memory");
        } else {
            asm volatile("s_waitcnt vmcnt(18)\ns_barrier" ::: "memory");
        }

        // (d) stream B fragments from ring slot cur; 4 MFMAs per ds_read.
        const char* Bsb = (const char*)Bs[cur];
        f32x4 acc[4][3];
#pragma unroll
        for (int pl = 0; pl < 4; ++pl)
#pragma unroll
            for (int u = 0; u < 3; ++u)
                acc[pl][u] = (f32x4){0.f, 0.f, 0.f, 0.f};

        __builtin_amdgcn_s_setprio(1);
#pragma unroll
        for (int ks = 0; ks < 8; ++ks) {
            int ci = (ks << 2) | quad;
            bf16x8 bfr[3];
#pragma unroll
            for (int u = 0; u < 3; ++u)
                if (useu[u])
                    bfr[u] = *(const bf16x8*)(Bsb + locB[u] * 512 + ((ci ^ keyB[u]) << 4));
#pragma unroll
            for (int u = 0; u < 3; ++u)
                if (useu[u]) {
#pragma unroll
                    for (int pl = 0; pl < 4; ++pl)
                        acc[pl][u] = __builtin_amdgcn_mfma_f32_16x16x32_bf16(
                            af[pl][ks], bfr[u], acc[pl][u], 0, 0, 0);
                }
        }
        __builtin_amdgcn_s_setprio(0);

        // Scatter band entries for all 4 planes. C/D: col n, row m = quad*4+r.
        // ox = 16*(u+1) + n - (i0+m) - 6; slab indexed by i = i0+m.
#pragma unroll
        for (int r = 0; r < 4; ++r) {
            int m = (quad << 2) + r;
            int io = i0 + m;
            int oxb = n - io - 6;
#pragma unroll
            for (int u = 0; u < 3; ++u) {
                if (!useu[u]) continue;
                int ox = 16 * (u + 1) + oxb;
                if (ox >= 0 && ox < NOFF) {
#pragma unroll
                    for (int pl = 0; pl < 4; ++pl)
                        sl[pl][ox][io] = acc[pl][u][r];
                }
            }
        }

        // (e) LDS drain + barrier: slab visible; all waves done with slot cur.
        asm volatile("s_waitcnt lgkmcnt(0)\ns_barrier" ::: "memory");

        // (g) prefetch image t+2 into slot cur (just freed).
        if (k + 2 < nv) STAGE(cur, t + 2);
        asm volatile("" ::: "memory");   // pin: stores below stay after prefetch

        // (f) stores: stale slab cells are exactly the out-of-range masked ones.
        // >=5 stores per wave per valid plane; >=1 valid plane per t.
#pragma unroll
        for (int pl = 0; pl < 4; ++pl) {
            int oyp = t - pl;
            if (oyp < Loj[pl] || oyp >= Hij[pl]) continue;   // wave-uniform
            int hp = hA + 2 * pl;
            int outb = ((b * 441 + oyp * NOFF) * H_ + hp) * W_;
#pragma unroll
            for (int jj = 0; jj < 6; ++jj) {
                int idx = tid + jj * 192;
                if (idx < NOFF * 48) {
                    int ox = idx / 48, i = idx - ox * 48;
                    int w = 2 * i + par;
                    int w2 = w + 2 * ox - 20;
                    float v = (w2 >= 0 && w2 < W_) ? sl[pl][ox][i] * (1.0f / 256.0f) : 0.0f;
                    out[outb + ox * (H_ * W_) + w] = v;
                }
            }
        }
    }
#undef STAGE
}

// ---------------------------------------------------------------------------
// Fallback (ws too small): direct fp32, slow but correct.
// ---------------------------------------------------------------------------
__global__ __launch_bounds__(256) void corr_fallback(const float* __restrict__ x1,
                                                     const float* __restrict__ x2,
                                                     float* __restrict__ out) {
    int bid = blockIdx.x;
    int oy = bid % NOFF, h = (bid / NOFF) % H_, b = bid / (NOFF * H_);
    int dy = 2 * oy - 20, h2 = h + dy;
    int outbase = ((b * 441 + oy * NOFF) * H_ + h) * W_;
    for (int idx = threadIdx.x; idx < NOFF * W_; idx += 256) {
        int ox = idx / W_, w = idx % W_;
        float acc = 0.f;
        int w2 = w + 2 * ox - 20;
        if (h2 >= 0 && h2 < H_ && w2 >= 0 && w2 < W_) {
            const float* p1 = x1 + (size_t)b * C_ * H_ * W_ + h * W_ + w;
            const float* p2 = x2 + (size_t)b * C_ * H_ * W_ + h2 * W_ + w2;
            for (int c = 0; c < C_; ++c) acc += p1[c * (H_ * W_)] * p2[c * (H_ * W_)];
        }
        out[outbase + ox * (H_ * W_) + w] = acc * (1.0f / 256.0f);
    }
}

extern "C" void kernel_launch(void* const* d_in, const int* in_sizes, int n_in,
                              void* d_out, int out_size, void* d_ws, size_t ws_size,
                              hipStream_t stream) {
    const float* x1 = (const float*)d_in[0];
    const float* x2 = (const float*)d_in[1];
    float* out = (float*)d_out;

    size_t need = (size_t)2 * X1T_ELEMS * sizeof(unsigned short);  // 37.7 MB
    if (ws_size >= need) {
        unsigned short* ws = (unsigned short*)d_ws;
        prep_kernel<<<B_ * H_ * 2 * 4, 256, 0, stream>>>(x1, x2, ws);
        corr_kernel<<<768, 192, 0, stream>>>(ws, out);
    } else {
        corr_fallback<<<B_ * H_ * NOFF, 256, 0, stream>>>(x1, x2, out);
    }
}

// Round 4
// 163.072 us; speedup vs baseline: 1.0775x; 1.0775x over previous
//
#include <hip/hip_runtime.h>
#include <hip/hip_bf16.h>

// FlowNetC correlation: B=4, C=256, H=W=96, PAD=MAX_DISP=20, STRIDE2=2, D=21.
// out[b, oy*21+ox, h, w] = (1/C) * sum_c x1[b,c,h,w] * x2[b,c,h+2oy-20,w+2ox-20]
//
// dx even -> split w by parity. Per (b,h,oy,par): out[i,e] = sum_c A[c,i]*B[c,i+e-10]
// (i=w>>1 in [0,48), e=ox). Band GEMM, MFMA 16x16x32 bf16.
//
// h-PAIRING: (h, oy=t) and (h+2, oy=t-1) share image x2[b, h+2t-20]. A block owns
// rows {hA, hA+2} and one oy-quarter; per image t it computes BOTH output planes:
// 2x MFMA per B-fragment ds_read, 1 image DMA + 2 barriers per 2 planes.
//
// ROUND-4 STRUCTURE: SINGLE 48KB image buffer + 16.3KB slab = 65.4KB LDS ->
// 2 blocks/CU co-resident (12 waves/CU). Rationale: the compiler's waitcnt pass
// must assume global_load_lds(Bs) aliases ds_read(Bs) and inserts its own
// conservative vmcnt wait before the fragment reads, so multi-buffer counted
// pipelines (R1/R3) never actually overlapped. Single-buffer makes the forced
// wait coincide with the required one; the CO-RESIDENT BLOCK provides the
// overlap (one block's MFMA phase hides the other's DMA/store/barrier phases).
// STAGE(t+1) issues right after the (e) barrier (buffer free), flying under
// this block's store phase + the partner block's compute.
//
// vmcnt ledger (per wave): P=8 gl2lds per image; stores of iter k are issued
// AFTER STAGE(t+1) (pin fence), count = (okA+okB)*jcnt >= 5 (every t has >=1
// valid plane). At (b) of iter k+1: vmcnt(5) retires P(k+1); k==0 uses
// vmcnt(0) (drains prologue STAGE + zero-fill stores, one-time). The
// compiler may strengthen the wait at the first ds_read; with a single
// buffer that is semantically the same wait.
//
// Global layout XOR-swizzle per row (chunk' = chunk ^ (row&31)): a wave's 64
// lanes map ds_read_b128 uniformly over the 8 bank-groups -> conflict-free.

typedef __bf16 bf16x8 __attribute__((ext_vector_type(8)));
typedef float f32x4 __attribute__((ext_vector_type(4)));

#define B_ 4
#define C_ 256
#define H_ 96
#define W_ 96
#define NOFF 21
#define ROWS 96                         // rows per (b,h) image = 2 par * 48
#define IMG_ELEMS (ROWS * C_)           // 24576 ushorts = 48KB
#define X1T_ELEMS (B_ * H_ * IMG_ELEMS) // 9,437,184 ushorts

__device__ __forceinline__ unsigned short f32_to_bf16_rne(float f) {
    union { float f; unsigned u; } v; v.f = f;
    unsigned u = v.u;
    return (unsigned short)((u + 0x7fffu + ((u >> 16) & 1u)) >> 16);
}

__device__ __forceinline__ void gl2lds16(const void* g, void* l) {
    __builtin_amdgcn_global_load_lds(
        (const __attribute__((address_space(1))) void*)g,
        (__attribute__((address_space(3))) void*)l, 16, 0, 0);
}

// ---------------------------------------------------------------------------
// Prep: fp32 NCHW -> bf16 swizzled-transposed [b][h][row][chunk^(row&31)]
// row = par*48 + (w>>1), par = w&1. One block per (b,h,src,c-block-of-64).
// ---------------------------------------------------------------------------
__global__ __launch_bounds__(256) void prep_kernel(const float* __restrict__ x1,
                                                   const float* __restrict__ x2,
                                                   unsigned short* __restrict__ ws) {
    __shared__ float tile[96 * 65];   // [w][c_local], pitch 65: conflict-free
    int bid = blockIdx.x;
    int cblk  = bid & 3;
    int which = (bid >> 2) & 1;
    int bh    = bid >> 3;             // 0..383
    int h = bh % H_;
    int b = bh / H_;
    int c0 = cblk << 6;

    const float* src = (which ? x2 : x1) + ((size_t)(b * C_ + c0) * H_ + h) * W_;
    unsigned short* dst = ws + (size_t)which * X1T_ELEMS + (size_t)(b * H_ + h) * IMG_ELEMS;

    // Phase A: coalesced global reads -> LDS [w][c]
    for (int idx = threadIdx.x; idx < 64 * 96; idx += 256) {
        int c = idx / 96, w = idx - c * 96;
        tile[w * 65 + c] = src[c * (H_ * W_) + w];
    }
    __syncthreads();

    // Phase B: pack 8 c -> 16B store. Per row this c-block lands in one
    // contiguous 128B run (aligned 8-chunk group XOR'd by row bits). Dest-driven.
    for (int idx = threadIdx.x; idx < 96 * 8; idx += 256) {
        int row = idx >> 3, tp = idx & 7;
        int par = row / 48, i = row - par * 48;
        int w = 2 * i + par;
        int s = tp ^ (row & 7);                 // source chunk within c-block
        const float* fsrc = &tile[w * 65 + (s << 3)];
        unsigned pk[4];
#pragma unroll
        for (int e = 0; e < 4; ++e) {
            unsigned lo = f32_to_bf16_rne(fsrc[2 * e]);
            unsigned hi = f32_to_bf16_rne(fsrc[2 * e + 1]);
            pk[e] = lo | (hi << 16);
        }
        int ccp = (((c0 >> 3) ^ (row & 24)) + tp);   // swizzled chunk position
        *(uint4*)((char*)(dst + (size_t)row * C_) + (ccp << 4)) =
            make_uint4(pk[0], pk[1], pk[2], pk[3]);
    }
}

// ---------------------------------------------------------------------------
// Main: block = (b, h-pair, oy-quarter). 6 waves = (par, mt). 2 blocks/CU.
// ---------------------------------------------------------------------------
__global__ __launch_bounds__(384, 3) void corr_kernel(const unsigned short* __restrict__ ws,
                                                      float* __restrict__ out) {
    __shared__ unsigned short Bs[IMG_ELEMS];      // 48KB, single buffer
    __shared__ float sl[2][NOFF][97];             // dual transpose slab (A,B rows)
    static_assert(sizeof(Bs) + sizeof(sl) <= 81920, "need 2 blocks/CU");

    int bid = blockIdx.x;
    int xcd = bid & 7, sidx = bid >> 3;        // XCD-aware: each XCD gets (b, h-half)
    int b  = xcd >> 1;
    int p  = ((xcd & 1) ? 24 : 0) + (sidx >> 2);   // pair index [0,48)
    int og = sidx & 3;                              // oy quarter
    int g = p >> 1, par_h = p & 1;
    int hA = 4 * g + par_h, hB = hA + 2;            // {h mod4 in 0,1} x {+2}
    int olo = (og * NOFF) >> 2;                     // 0,5,10,15
    int ohi = ((og + 1) * NOFF) >> 2;               // 5,10,15,21

    int tid = threadIdx.x;
    int wv = tid >> 6, lane = tid & 63;
    int par = wv & 1, mt = wv >> 1;
    int i0 = mt << 4;
    int n = lane & 15, quad = lane >> 4;

    // Hoisted epilogue addressing: idx = tid + 384j, j < jcnt (5 or 6).
    int jcnt = 5 + (tid < 96 ? 1 : 0);
    int slotj[6], offj[6]; bool mj[6];
#pragma unroll
    for (int j = 0; j < 6; ++j) {
        int idx = tid + j * 384;
        int ox = idx / W_, w = idx - ox * W_;
        slotj[j] = ox * 97 + w;
        offj[j]  = ox * (H_ * W_) + w;
        int w2 = w + 2 * ox - 20;
        mj[j] = (w2 >= 0) & (w2 < W_);
    }

    // A fragments for BOTH rows: loaded once, reused for all t.
    int rowA = par * 48 + i0 + n;
    int keyA = rowA & 31;
    const unsigned short* AgA = ws + (size_t)(b * H_ + hA) * IMG_ELEMS + (size_t)rowA * C_;
    const unsigned short* AgB = ws + (size_t)(b * H_ + hB) * IMG_ELEMS + (size_t)rowA * C_;
    bf16x8 afA[8], afB[8];
#pragma unroll
    for (int ks = 0; ks < 8; ++ks) {
        int o = (((ks << 2) | quad) ^ keyA) << 3;
        afA[ks] = *(const bf16x8*)(AgA + o);
        afB[ks] = *(const bf16x8*)(AgB + o);
    }
    // Drain A loads with a compiler-visible wait BEFORE any DMA is issued so
    // no A-related vmcnt wait lands inside the loop.
    asm volatile("" ::: "memory");
    __builtin_amdgcn_s_waitcnt(0);

    const unsigned short* Bimg = ws + (size_t)X1T_ELEMS + (size_t)(b * H_) * IMG_ELEMS;

    int rowB0 = par * 48 + n;          // u=0 (j 0..15)
    int rowB1 = rowB0 + 16;            // u=1
    int rowB2 = rowB0 + 32;            // u=2
    int keyB0 = rowB0 & 31, keyB1 = rowB1 & 31, keyB2 = rowB2 & 31;

    // Valid oy bands per row (clip h2 in range AND og quarter).
    int aLo = (hA <= 20) ? ((21 - hA) >> 1) : 0; if (aLo < olo) aLo = olo;
    int aHi = ((115 - hA) >> 1) + 1;             if (aHi > ohi) aHi = ohi;
    if (aHi < aLo) aHi = aLo;
    int bLo = (hB <= 20) ? ((21 - hB) >> 1) : 0; if (bLo < olo) bLo = olo;
    int bHi = ((115 - hB) >> 1) + 1;             if (bHi > ohi) bHi = ohi;
    if (bHi < bLo) bHi = bLo;

    // Image parameter t: planeA oy=t (t in [aLo,aHi)), planeB oy=t-1
    // (t in [bLo+1,bHi+1)). Union is contiguous (starts/ends differ by <=1),
    // and every t in it has >=1 valid plane (ledger relies on this).
    int tlo, thi;
    bool ea = (aLo >= aHi), eb = (bLo >= bHi);
    if (ea && eb)      { tlo = 0; thi = 0; }
    else if (ea)       { tlo = bLo + 1; thi = bHi + 1; }
    else if (eb)       { tlo = aLo; thi = aHi; }
    else {
        tlo = (aLo < bLo + 1) ? aLo : bLo + 1;
        thi = (aHi > bHi + 1) ? aHi : bHi + 1;
    }
    int nv = thi - tlo;

    int wvoff  = wv * 8192;            // wave-uniform LDS base offset (6 waves x 8KB)
    int gmaoff = wvoff + lane * 16;    // per-lane global offset

#define STAGE(tt) do {                                                                \
    const char* Bg_ = (const char*)(Bimg + (size_t)(hA + 2 * (tt) - 20) * IMG_ELEMS); \
    _Pragma("unroll")                                                                 \
    for (int c = 0; c < 8; ++c)                                                       \
        gl2lds16(Bg_ + gmaoff + c * 1024, (char*)Bs + wvoff + c * 1024);              \
} while (0)

    // Prologue: stage first image, then zero-fill OOB planes while it flies.
    if (nv > 0) STAGE(tlo);
    asm volatile("" ::: "memory");   // pin: zero-fill stores stay after the STAGE

    for (int oy = olo; oy < ohi; ++oy) {
        if (oy < aLo || oy >= aHi) {
            int outb = ((b * 441 + oy * NOFF) * H_ + hA) * W_;
#pragma unroll
            for (int j = 0; j < 6; ++j) if (j < jcnt) out[outb + offj[j]] = 0.0f;
        }
        if (oy < bLo || oy >= bHi) {
            int outb = ((b * 441 + oy * NOFF) * H_ + hB) * W_;
#pragma unroll
            for (int j = 0; j < 6; ++j) if (j < jcnt) out[outb + offj[j]] = 0.0f;
        }
    }

    const float* slA = &sl[0][0][0];
    const float* slB = &sl[1][0][0];

    for (int k = 0; k < nv; ++k) {
        int t = tlo + k;

        // (b) wait for this image's DMA + barrier. Steady: vmcnt(5) retires
        // P(k) while leaving ~5 of last iter's stores in flight.
        if (k == 0) asm volatile("s_waitcnt vmcnt(0)\ns_barrier" ::: "memory");
        else        asm volatile("s_waitcnt vmcnt(5)\ns_barrier" ::: "memory");

        // (d) batch-load B fragments, then MFMA burst for BOTH A-sets.
        const char* Bsb = (const char*)Bs;
        f32x4 aA0 = {0.f,0.f,0.f,0.f}, aA1 = {0.f,0.f,0.f,0.f}, aA2 = {0.f,0.f,0.f,0.f};
        f32x4 aB0 = {0.f,0.f,0.f,0.f}, aB1 = {0.f,0.f,0.f,0.f}, aB2 = {0.f,0.f,0.f,0.f};

        __builtin_amdgcn_s_setprio(1);
        if (mt == 0) {
            bf16x8 f0[8], f1[8];
#pragma unroll
            for (int ks = 0; ks < 8; ++ks) {
                int ci = (ks << 2) | quad;
                f0[ks] = *(const bf16x8*)(Bsb + rowB0 * 512 + ((ci ^ keyB0) << 4));
                f1[ks] = *(const bf16x8*)(Bsb + rowB1 * 512 + ((ci ^ keyB1) << 4));
            }
#pragma unroll
            for (int ks = 0; ks < 8; ++ks) {
                aA0 = __builtin_amdgcn_mfma_f32_16x16x32_bf16(afA[ks], f0[ks], aA0, 0, 0, 0);
                aA1 = __builtin_amdgcn_mfma_f32_16x16x32_bf16(afA[ks], f1[ks], aA1, 0, 0, 0);
                aB0 = __builtin_amdgcn_mfma_f32_16x16x32_bf16(afB[ks], f0[ks], aB0, 0, 0, 0);
                aB1 = __builtin_amdgcn_mfma_f32_16x16x32_bf16(afB[ks], f1[ks], aB1, 0, 0, 0);
            }
        } else if (mt == 1) {
            bf16x8 f0[8], f1[8], f2[8];
#pragma unroll
            for (int ks = 0; ks < 8; ++ks) {
                int ci = (ks << 2) | quad;
                f0[ks] = *(const bf16x8*)(Bsb + rowB0 * 512 + ((ci ^ keyB0) << 4));
                f1[ks] = *(const bf16x8*)(Bsb + rowB1 * 512 + ((ci ^ keyB1) << 4));
                f2[ks] = *(const bf16x8*)(Bsb + rowB2 * 512 + ((ci ^ keyB2) << 4));
            }
#pragma unroll
            for (int ks = 0; ks < 8; ++ks) {
                aA0 = __builtin_amdgcn_mfma_f32_16x16x32_bf16(afA[ks], f0[ks], aA0, 0, 0, 0);
                aA1 = __builtin_amdgcn_mfma_f32_16x16x32_bf16(afA[ks], f1[ks], aA1, 0, 0, 0);
                aA2 = __builtin_amdgcn_mfma_f32_16x16x32_bf16(afA[ks], f2[ks], aA2, 0, 0, 0);
                aB0 = __builtin_amdgcn_mfma_f32_16x16x32_bf16(afB[ks], f0[ks], aB0, 0, 0, 0);
                aB1 = __builtin_amdgcn_mfma_f32_16x16x32_bf16(afB[ks], f1[ks], aB1, 0, 0, 0);
                aB2 = __builtin_amdgcn_mfma_f32_16x16x32_bf16(afB[ks], f2[ks], aB2, 0, 0, 0);
            }
        } else {
            bf16x8 f1[8], f2[8];
#pragma unroll
            for (int ks = 0; ks < 8; ++ks) {
                int ci = (ks << 2) | quad;
                f1[ks] = *(const bf16x8*)(Bsb + rowB1 * 512 + ((ci ^ keyB1) << 4));
                f2[ks] = *(const bf16x8*)(Bsb + rowB2 * 512 + ((ci ^ keyB2) << 4));
            }
#pragma unroll
            for (int ks = 0; ks < 8; ++ks) {
                aA1 = __builtin_amdgcn_mfma_f32_16x16x32_bf16(afA[ks], f1[ks], aA1, 0, 0, 0);
                aA2 = __builtin_amdgcn_mfma_f32_16x16x32_bf16(afA[ks], f2[ks], aA2, 0, 0, 0);
                aB1 = __builtin_amdgcn_mfma_f32_16x16x32_bf16(afB[ks], f1[ks], aB1, 0, 0, 0);
                aB2 = __builtin_amdgcn_mfma_f32_16x16x32_bf16(afB[ks], f2[ks], aB2, 0, 0, 0);
            }
        }
        __builtin_amdgcn_s_setprio(0);

        // Scatter both planes (in-band cell set is t-invariant, so stale
        // entries are exactly the out-of-range masked ones).
        // C/D: col n = lane&15, row m = quad*4+r. ox = 16*(u+1) + n - (i0+m) - 6.
#pragma unroll
        for (int r = 0; r < 4; ++r) {
            int m = (quad << 2) + r;
            int w = 2 * (i0 + m) + par;
            int oxb = n - i0 - m - 6;
            if (mt != 2) { int ox = 16 + oxb; if (ox >= 0 && ox < NOFF) { sl[0][ox][w] = aA0[r]; sl[1][ox][w] = aB0[r]; } }
            {             int ox = 32 + oxb; if (ox >= 0 && ox < NOFF) { sl[0][ox][w] = aA1[r]; sl[1][ox][w] = aB1[r]; } }
            if (mt != 0) { int ox = 48 + oxb; if (ox >= 0 && ox < NOFF) { sl[0][ox][w] = aA2[r]; sl[1][ox][w] = aB2[r]; } }
        }

        // (e) LDS drain + barrier: slab visible; ALL waves done reading Bs,
        // so the buffer is free for the next image.
        asm volatile("s_waitcnt lgkmcnt(0)\ns_barrier" ::: "memory");

        // (g) stage image t+1 into the (now free) buffer; flies under this
        // block's store phase + the co-resident block's compute phase.
        if (k + 1 < nv) STAGE(t + 1);
        asm volatile("" ::: "memory");   // pin: stores below stay after the STAGE

        // (f) batched slab reads, then plane-masked stores (>=5 per wave,
        // required by the vmcnt ledger; >=1 plane valid per t by construction).
        bool okA = (t >= aLo) & (t < aHi);
        bool okB = (t - 1 >= bLo) & (t - 1 < bHi);
        int outbA = ((b * 441 + t * NOFF) * H_ + hA) * W_;
        int outbB = ((b * 441 + (t - 1) * NOFF) * H_ + hB) * W_;

        float vA[6], vB[6];
#pragma unroll
        for (int j = 0; j < 6; ++j) if (j < jcnt) {
            vA[j] = mj[j] ? slA[slotj[j]] * (1.0f / 256.0f) : 0.0f;
            vB[j] = mj[j] ? slB[slotj[j]] * (1.0f / 256.0f) : 0.0f;
        }
        if (okA) {
#pragma unroll
            for (int j = 0; j < 6; ++j) if (j < jcnt) out[outbA + offj[j]] = vA[j];
        }
        if (okB) {
#pragma unroll
            for (int j = 0; j < 6; ++j) if (j < jcnt) out[outbB + offj[j]] = vB[j];
        }
    }
#undef STAGE
}

// ---------------------------------------------------------------------------
// Fallback (ws too small): direct fp32, slow but correct.
// ---------------------------------------------------------------------------
__global__ __launch_bounds__(256) void corr_fallback(const float* __restrict__ x1,
                                                     const float* __restrict__ x2,
                                                     float* __restrict__ out) {
    int bid = blockIdx.x;
    int oy = bid % NOFF, h = (bid / NOFF) % H_, b = bid / (NOFF * H_);
    int dy = 2 * oy - 20, h2 = h + dy;
    int outbase = ((b * 441 + oy * NOFF) * H_ + h) * W_;
    for (int idx = threadIdx.x; idx < NOFF * W_; idx += 256) {
        int ox = idx / W_, w = idx % W_;
        float acc = 0.f;
        int w2 = w + 2 * ox - 20;
        if (h2 >= 0 && h2 < H_ && w2 >= 0 && w2 < W_) {
            const float* p1 = x1 + (size_t)b * C_ * H_ * W_ + h * W_ + w;
            const float* p2 = x2 + (size_t)b * C_ * H_ * W_ + h2 * W_ + w2;
            for (int c = 0; c < C_; ++c) acc += p1[c * (H_ * W_)] * p2[c * (H_ * W_)];
        }
        out[outbase + ox * (H_ * W_) + w] = acc * (1.0f / 256.0f);
    }
}

extern "C" void kernel_launch(void* const* d_in, const int* in_sizes, int n_in,
                              void* d_out, int out_size, void* d_ws, size_t ws_size,
                              hipStream_t stream) {
    const float* x1 = (const float*)d_in[0];
    const float* x2 = (const float*)d_in[1];
    float* out = (float*)d_out;

    size_t need = (size_t)2 * X1T_ELEMS * sizeof(unsigned short);  // 37.7 MB
    if (ws_size >= need) {
        unsigned short* ws = (unsigned short*)d_ws;
        prep_kernel<<<B_ * H_ * 2 * 4, 256, 0, stream>>>(x1, x2, ws);
        corr_kernel<<<768, 384, 0, stream>>>(ws, out);
    } else {
        corr_fallback<<<B_ * H_ * NOFF, 256, 0, stream>>>(x1, x2, out);
    }
}